// Round 12
// baseline (348.185 us; speedup 1.0000x reference)
//
#include <hip/hip_runtime.h>
#include <hip/hip_bf16.h>
#include <stdint.h>
#include <type_traits>

// ---------------------------------------------------------------------------
// MultiExpertMoELayer: opcode-routed 2-stage FFN chain.
//   op = argmax(x[0,0,0:8]);  for e in 0..1: x = gelu(x@W1[op,e]+b1)@W2[op,e]+b2
// Round 12 (base = R7, 338us best):
//   R11 post-mortem: 4-phase on GEMM1 (K=1024) = null. Catalog cross-check:
//   phase-pipeline gains need DEEP K (m201 1563TF @K=4096; at K=1024 the
//   same-probe 8ph reference is 848TF -- my loose GEMM1 already runs ~900).
//   -> single change: GEMM2 (K=4096, 64 K-tiles) gets the phase discipline.
//      Keep R7 staging skeleton exactly (full-tile stage at top, vmcnt(6),
//      never drained mid-loop); split tile body into 2 barriered phases:
//      {reads(ks) ; setprio(1) 16 MFMA setprio(0) ; SBAR}. No sched_barrier,
//      no mid-tile lgkm drain (compiler orders reads->MFMA).
//   GEMM1: R7 loose, unchanged.
// Canary: absmax must stay exactly 0.01171875 (accumulation DAG unchanged).
// ---------------------------------------------------------------------------

typedef __attribute__((ext_vector_type(8))) short short8;   // 8 x bf16 (4 VGPR)
typedef __attribute__((ext_vector_type(4))) float f32x4;    // MFMA accum

#define LGKM0  asm volatile("s_waitcnt lgkmcnt(0)" ::: "memory")
#define SBAR   __builtin_amdgcn_s_barrier()

template<int VM> __device__ __forceinline__ void wait_vm() {
  if constexpr (VM == 8)      asm volatile("s_waitcnt vmcnt(8)" ::: "memory");
  else if constexpr (VM == 6) asm volatile("s_waitcnt vmcnt(6)" ::: "memory");
  else                        asm volatile("s_waitcnt vmcnt(0)" ::: "memory");
}

__device__ __forceinline__ unsigned short f2bf(float f) {
  union { float f; uint32_t u; } v; v.f = f;
  return (unsigned short)((v.u + 0x7fffu + ((v.u >> 16) & 1u)) >> 16);  // RNE
}

// jax.nn.gelu(approximate=True): 0.5x(1+tanh(sqrt(2/pi)(x+0.044715x^3)))
__device__ __forceinline__ float gelu_tanh(float x) {
  float u = 0.7978845608028654f * (x + 0.044715f * x * x * x);
  float e = __expf(2.0f * u);
  float t = 1.0f - 2.0f / (e + 1.0f);   // tanh(u), safe at +/-inf
  return 0.5f * x * (1.0f + t);
}

__device__ __forceinline__ void gload_lds16(const void* g, void* l) {
  __builtin_amdgcn_global_load_lds(
      (const __attribute__((address_space(1))) void*)g,
      (__attribute__((address_space(3))) void*)l, 16, 0, 0);
}

// op = argmax(x[0,0,0:8]), first-max wins (matches jnp.argmax).
__device__ __forceinline__ int compute_op(const float* __restrict__ x) {
  int best = 0; float bv = x[0];
#pragma unroll
  for (int i = 1; i < 8; ++i) { float v = x[i]; if (v > bv) { bv = v; best = i; } }
  return best;
}

// --------------------------- fused prep kernel ------------------------------
// blocks [0, 4096)   : x fp32 -> bf16 (8 elems/thread)
// blocks [4096, 8192): 4 transpose+cvt jobs of 1024 blocks each
__global__ __launch_bounds__(256) void prep_kernel(
    const float* __restrict__ x, const float* __restrict__ W1,
    const float* __restrict__ W2,
    unsigned short* __restrict__ xb, unsigned short* __restrict__ w1t,
    unsigned short* __restrict__ w2t) {
  __shared__ float tile[64][65];
  const int bid = blockIdx.x;
  const int t = threadIdx.x;
  if (bid < 4096) {
    const int i = bid * 256 + t;
    const float4* xv = (const float4*)x;
    float4 v0 = xv[i * 2], v1 = xv[i * 2 + 1];
    ushort4 o0, o1;
    o0.x = f2bf(v0.x); o0.y = f2bf(v0.y); o0.z = f2bf(v0.z); o0.w = f2bf(v0.w);
    o1.x = f2bf(v1.x); o1.y = f2bf(v1.y); o1.z = f2bf(v1.z); o1.w = f2bf(v1.w);
    ((ushort4*)xb)[i * 2] = o0; ((ushort4*)xb)[i * 2 + 1] = o1;
    return;
  }
  const int op = compute_op(x);
  const int j = bid - 4096;
  const int job = j >> 10, w = j & 1023;
  const int e = job & 1;
  const bool isW1 = (job < 2);
  const int R = isW1 ? 1024 : 4096;
  const int C = isW1 ? 4096 : 1024;
  const float* W = (isW1 ? W1 : W2) + ((size_t)op * 2 + (size_t)e) * (size_t)R * C;
  unsigned short* dst0 = (isW1 ? w1t : w2t) + (size_t)e * 4096 * 1024;
  const int tc = w % (C >> 6), tr = w / (C >> 6);
  {
    const int r  = t >> 2;
    const int c0 = (t & 3) * 16;
    const float* src = W + (size_t)(tr * 64 + r) * C + tc * 64 + c0;
#pragma unroll
    for (int jj = 0; jj < 16; jj += 4) {
      float4 v = *(const float4*)(src + jj);
      tile[r][c0 + jj]     = v.x;
      tile[r][c0 + jj + 1] = v.y;
      tile[r][c0 + jj + 2] = v.z;
      tile[r][c0 + jj + 3] = v.w;
    }
  }
  __syncthreads();
  {
    const int c  = t >> 2;
    const int r0 = (t & 3) * 16;
    unsigned short* dp = dst0 + (size_t)(tc * 64 + c) * R + tr * 64 + r0;
#pragma unroll
    for (int jj = 0; jj < 16; jj += 4) {
      ushort4 o;
      o.x = f2bf(tile[r0 + jj][c]);
      o.y = f2bf(tile[r0 + jj + 1][c]);
      o.z = f2bf(tile[r0 + jj + 2][c]);
      o.w = f2bf(tile[r0 + jj + 3][c]);
      *(ushort4*)(dp + jj) = o;
    }
  }
}

// --------------------------- shared staging ---------------------------------
// LDS per buffer: A [BM][64] + B [BN][64] bf16; 16B chunk c of row r stored
// at c ^ (r&7) (both-sides swizzle with pre-swizzled staging source).
template<int BM, int BN>
__device__ __forceinline__ void stage_tile_all(
    const unsigned short* __restrict__ Ab,
    const unsigned short* __restrict__ Bb,
    int K, int kb, short* __restrict__ dst, int tid) {
  constexpr int SA = BM / 64, SB = BN / 64, ABK = BM * 64;
#pragma unroll
  for (int j = 0; j < SA; ++j) {
    const int ci = j * 512 + tid;
    const int row = ci >> 3;
    const int gc = (ci & 7) ^ (row & 7);
    gload_lds16(Ab + (size_t)row * K + kb + gc * 8, dst + ci * 8);
  }
#pragma unroll
  for (int j = 0; j < SB; ++j) {
    const int cj = j * 512 + tid;
    const int row = cj >> 3;
    const int gc = (cj & 7) ^ (row & 7);
    gload_lds16(Bb + (size_t)row * K + kb + gc * 8, dst + ABK + cj * 8);
  }
}

// --------------------------- GEMM1: R7 loose (unchanged, 338us best) --------
// 256x256, 8 waves 2Mx4N, per-wave 128x64; bm-slow XCD chunks.
template<bool GELU, typename OUT_T>
__global__ __launch_bounds__(512, 2) void gemm1_loose(
    const unsigned short* __restrict__ A,
    const unsigned short* __restrict__ Bt,
    const float* __restrict__ x_op,
    const float* __restrict__ bias_base,     // [8][2][N]
    int expert, OUT_T* __restrict__ Cout, int M, int N, int K)
{
  constexpr int BM = 256, BN = 256, BK = 64;
  constexpr int MR = 8, NR = 4, S = 8;
  constexpr int BUF = (BM + BN) * BK;
  __shared__ short smem[2 * BUF];

  const int tid  = threadIdx.x;
  const int wid  = tid >> 6, lane = tid & 63;
  const int wm   = wid >> 2, wn = wid & 3;
  const int lq   = lane >> 4, lr = lane & 15;

  const int nwg = gridDim.x;
  const int id  = blockIdx.x;
  const int s   = (id & 7) * (nwg >> 3) + (id >> 3);
  const int nbn = N / BN;
  const int bm  = s / nbn, bn = s % nbn;

  const unsigned short* Ab = A  + (size_t)bm * BM * K;
  const unsigned short* Bb = Bt + (size_t)bn * BN * K;

  f32x4 acc[MR][NR] = {};

  stage_tile_all<BM, BN>(Ab, Bb, K, 0, smem, tid);

  const int nkt = K / BK;
  for (int t = 0; t < nkt; ++t) {
    const char* cA = (const char*)(smem + (t & 1) * BUF);
    const char* cB = cA + BM * BK * 2;
    short* nxt = smem + ((t + 1) & 1) * BUF;

    if (t + 1 < nkt) { stage_tile_all<BM, BN>(Ab, Bb, K, (t + 1) * BK, nxt, tid); wait_vm<S>(); }
    else             { wait_vm<0>(); }
    SBAR;

#pragma unroll
    for (int ks = 0; ks < 2; ++ks) {
      short8 bf[NR];
#pragma unroll
      for (int n = 0; n < NR; ++n) {
        const int rb = wn * 64 + n * 16 + lr;
        const int ch = ((ks << 2) | lq) ^ (rb & 7);
        bf[n] = *(const short8*)(cB + rb * 128 + ch * 16);
      }
#pragma unroll
      for (int mh = 0; mh < 2; ++mh) {
        short8 af[MR / 2];
#pragma unroll
        for (int mm = 0; mm < MR / 2; ++mm) {
          const int ra = wm * 128 + (mh * (MR / 2) + mm) * 16 + lr;
          const int ch = ((ks << 2) | lq) ^ (ra & 7);
          af[mm] = *(const short8*)(cA + ra * 128 + ch * 16);
        }
#pragma unroll
        for (int mm = 0; mm < MR / 2; ++mm)
#pragma unroll
          for (int n = 0; n < NR; ++n)
            acc[mh * (MR / 2) + mm][n] = __builtin_amdgcn_mfma_f32_16x16x32_bf16(
                af[mm], bf[n], acc[mh * (MR / 2) + mm][n], 0, 0, 0);
      }
    }

    LGKM0;
    SBAR;
  }

  const int op = compute_op(x_op);
  const float* bias = bias_base + ((size_t)op * 2 + (size_t)expert) * (size_t)N;
#pragma unroll
  for (int f = 0; f < MR; ++f) {
    const int grow0 = bm * BM + wm * 128 + f * 16 + lq * 4;
#pragma unroll
    for (int n = 0; n < NR; ++n) {
      const int gcol = bn * BN + wn * 64 + n * 16 + lr;
      const float bv = bias[gcol];
#pragma unroll
      for (int r = 0; r < 4; ++r) {
        float v = acc[f][n][r] + bv;
        if constexpr (GELU) v = gelu_tanh(v);
        const size_t off = (size_t)(grow0 + r) * N + gcol;
        if constexpr (std::is_same<OUT_T, float>::value) Cout[off] = v;
        else Cout[off] = f2bf(v);
      }
    }
  }
}

// --------------------------- GEMM2: deep-K phased ---------------------------
// 128x256, 8 waves 2Mx4N, per-wave 64x64; bn-slow; K=4096 = 64 K-tiles.
// R7 staging skeleton (full-tile stage at top, vmcnt(6), never drained
// mid-loop) + 2 barriered setprio phases per tile (the single new variable).
template<bool GELU, typename OUT_T>
__global__ __launch_bounds__(512, 2) void gemm2_phased(
    const unsigned short* __restrict__ A,
    const unsigned short* __restrict__ Bt,
    const float* __restrict__ x_op,
    const float* __restrict__ bias_base,     // [8][2][N]
    int expert, OUT_T* __restrict__ Cout, int M, int N, int K)
{
  constexpr int BM = 128, BN = 256, BK = 64;
  constexpr int MR = 4, NR = 4, S = 6;
  constexpr int BUF = (BM + BN) * BK;
  __shared__ short smem[2 * BUF];

  const int tid  = threadIdx.x;
  const int wid  = tid >> 6, lane = tid & 63;
  const int wm   = wid >> 2, wn = wid & 3;
  const int lq   = lane >> 4, lr = lane & 15;

  const int nwg = gridDim.x;
  const int id  = blockIdx.x;
  const int s   = (id & 7) * (nwg >> 3) + (id >> 3);
  const int nbm = M / BM;
  const int bn  = s / nbm, bm = s % nbm;   // bn-slow: B panel L2-resident

  const unsigned short* Ab = A  + (size_t)bm * BM * K;
  const unsigned short* Bb = Bt + (size_t)bn * BN * K;

  f32x4 acc[MR][NR] = {};

  stage_tile_all<BM, BN>(Ab, Bb, K, 0, smem, tid);

  const int nkt = K / BK;
  for (int t = 0; t < nkt; ++t) {
    const char* cA = (const char*)(smem + (t & 1) * BUF);
    const char* cB = cA + BM * BK * 2;
    short* nxt = smem + ((t + 1) & 1) * BUF;

    if (t + 1 < nkt) { stage_tile_all<BM, BN>(Ab, Bb, K, (t + 1) * BK, nxt, tid); wait_vm<S>(); }
    else             { wait_vm<0>(); }
    SBAR;

    // --- two barriered phases per K-tile (ks = 0, 1), 16 MFMA each ---
#pragma unroll
    for (int ks = 0; ks < 2; ++ks) {
      short8 bf[NR], af[MR];
#pragma unroll
      for (int n = 0; n < NR; ++n) {
        const int rb = wn * 64 + n * 16 + lr;
        const int ch = ((ks << 2) | lq) ^ (rb & 7);
        bf[n] = *(const short8*)(cB + rb * 128 + ch * 16);
      }
#pragma unroll
      for (int mm = 0; mm < MR; ++mm) {
        const int ra = wm * 64 + mm * 16 + lr;
        const int ch = ((ks << 2) | lq) ^ (ra & 7);
        af[mm] = *(const short8*)(cA + ra * 128 + ch * 16);
      }
      __builtin_amdgcn_s_setprio(1);
#pragma unroll
      for (int mm = 0; mm < MR; ++mm)
#pragma unroll
        for (int n = 0; n < NR; ++n)
          acc[mm][n] = __builtin_amdgcn_mfma_f32_16x16x32_bf16(
              af[mm], bf[n], acc[mm][n], 0, 0, 0);
      __builtin_amdgcn_s_setprio(0);
      if (ks == 0) SBAR;     // phase boundary (no lgkm drain: data not reused)
    }

    LGKM0;
    SBAR;
  }

  const int op = compute_op(x_op);
  const float* bias = bias_base + ((size_t)op * 2 + (size_t)expert) * (size_t)N;
#pragma unroll
  for (int f = 0; f < MR; ++f) {
    const int grow0 = bm * BM + wm * 64 + f * 16 + lq * 4;
#pragma unroll
    for (int n = 0; n < NR; ++n) {
      const int gcol = bn * BN + wn * 64 + n * 16 + lr;
      const float bv = bias[gcol];
#pragma unroll
      for (int r = 0; r < 4; ++r) {
        float v = acc[f][n][r] + bv;
        if constexpr (GELU) v = gelu_tanh(v);
        const size_t off = (size_t)(grow0 + r) * N + gcol;
        if constexpr (std::is_same<OUT_T, float>::value) Cout[off] = v;
        else Cout[off] = f2bf(v);
      }
    }
  }
}

// --------------------------- launcher ---------------------------------------
extern "C" void kernel_launch(void* const* d_in, const int* in_sizes, int n_in,
                              void* d_out, int out_size, void* d_ws, size_t ws_size,
                              hipStream_t stream) {
  const float* x  = (const float*)d_in[0];
  const float* W1 = (const float*)d_in[1];   // [8][2][1024][4096]
  const float* b1 = (const float*)d_in[2];   // [8][2][4096]
  const float* W2 = (const float*)d_in[3];   // [8][2][4096][1024]
  const float* b2 = (const float*)d_in[4];   // [8][2][1024]
  float* out = (float*)d_out;

  const int D = 1024, F = 4096, M = 8192;    // M = B*S = 4*2048

  // ws layout: [xb 16.8MB][w1t 16.8MB][w2t 16.8MB][h 67.1MB]
  char* ws = (char*)d_ws;
  unsigned short* xb  = (unsigned short*)ws;
  unsigned short* w1t = (unsigned short*)(ws + (size_t)M * D * 2);
  unsigned short* w2t = (unsigned short*)(ws + (size_t)M * D * 2 + (size_t)2 * D * F * 2);
  unsigned short* h   = (unsigned short*)(ws + (size_t)M * D * 2 + (size_t)4 * D * F * 2);
  unsigned short* x1b = (unsigned short*)d_out;  // stage-0 output parked in d_out

  prep_kernel<<<4096 + 4 * 1024, 256, 0, stream>>>(x, W1, W2, xb, w1t, w2t);

  // GEMM1: M=8192,N=4096,K=1024  256x256 loose,  grid 512
  // GEMM2: M=8192,N=1024,K=4096  128x256 phased, grid 256
  // expert 0
  gemm1_loose<true,  unsigned short><<<(M/256)*(F/256), 512, 0, stream>>>(xb,  w1t,                 x, b1, 0, h,   M, F, D);
  gemm2_phased<false, unsigned short><<<(M/128)*(D/256), 512, 0, stream>>>(h,   w2t,                 x, b2, 0, x1b, M, D, F);
  // expert 1
  gemm1_loose<true,  unsigned short><<<(M/256)*(F/256), 512, 0, stream>>>(x1b, w1t + (size_t)F * D, x, b1, 1, h,   M, F, D);
  gemm2_phased<false, float         ><<<(M/128)*(D/256), 512, 0, stream>>>(h,   w2t + (size_t)D * F, x, b2, 1, out, M, D, F);
}

// Round 13
// 339.005 us; speedup vs baseline: 1.0271x; 1.0271x over previous
//
#include <hip/hip_runtime.h>
#include <hip/hip_bf16.h>
#include <stdint.h>
#include <type_traits>

// ---------------------------------------------------------------------------
// MultiExpertMoELayer: opcode-routed 2-stage FFN chain.
//   op = argmax(x[0,0,0:8]);  for e in 0..1: x = gelu(x@W1[op,e]+b1)@W2[op,e]+b2
// FINAL (= Round 7 kernel, best of 12 structural variants at 338us):
//   - one fused prep dispatch: x fp32->bf16 + 4 opcode-selected weight
//     transpose/convert jobs (argmax recomputed per block, no host sync)
//   - GEMM1 (M8192 N4096 K1024): 256x256 tile, 8 waves 2Mx4N, loose sync
//   - GEMM2 (M8192 N1024 K4096): 128x256 tile, bn-slow XCD chunks
//   - both: full-tile global_load_lds prefetch issued at tile top, counted
//     vmcnt(S) never drained mid-loop (T4), raw s_barrier (no implicit
//     vmcnt(0) drain), single lgkmcnt(0)+barrier per tile, NO intra-tile
//     pins (sched_barrier poison per m141; R2-R6 lockstep variants all lost)
//   - chunk-XOR LDS swizzle, both-sides (G21), zero bank conflicts
// Structure A/B history: coarse-pipe 381, thin-phase 359, 32x32 393, flat-B
// 406/474, 2blk/CU 374, 4-phase 343, deep-K-phased 348 -> loose 338 wins.
// Canary: absmax = 0.01171875.
// ---------------------------------------------------------------------------

typedef __attribute__((ext_vector_type(8))) short short8;   // 8 x bf16 (4 VGPR)
typedef __attribute__((ext_vector_type(4))) float f32x4;    // MFMA accum

#define LGKM0  asm volatile("s_waitcnt lgkmcnt(0)" ::: "memory")
#define SBAR   __builtin_amdgcn_s_barrier()

template<int VM> __device__ __forceinline__ void wait_vm() {
  if constexpr (VM == 8)      asm volatile("s_waitcnt vmcnt(8)" ::: "memory");
  else if constexpr (VM == 6) asm volatile("s_waitcnt vmcnt(6)" ::: "memory");
  else                        asm volatile("s_waitcnt vmcnt(0)" ::: "memory");
}

__device__ __forceinline__ unsigned short f2bf(float f) {
  union { float f; uint32_t u; } v; v.f = f;
  return (unsigned short)((v.u + 0x7fffu + ((v.u >> 16) & 1u)) >> 16);  // RNE
}

// jax.nn.gelu(approximate=True): 0.5x(1+tanh(sqrt(2/pi)(x+0.044715x^3)))
__device__ __forceinline__ float gelu_tanh(float x) {
  float u = 0.7978845608028654f * (x + 0.044715f * x * x * x);
  float e = __expf(2.0f * u);
  float t = 1.0f - 2.0f / (e + 1.0f);   // tanh(u), safe at +/-inf
  return 0.5f * x * (1.0f + t);
}

__device__ __forceinline__ void gload_lds16(const void* g, void* l) {
  __builtin_amdgcn_global_load_lds(
      (const __attribute__((address_space(1))) void*)g,
      (__attribute__((address_space(3))) void*)l, 16, 0, 0);
}

// op = argmax(x[0,0,0:8]), first-max wins (matches jnp.argmax). Uniform,
// 8 L2-hot scalar loads -- cheap enough to recompute per block.
__device__ __forceinline__ int compute_op(const float* __restrict__ x) {
  int best = 0; float bv = x[0];
#pragma unroll
  for (int i = 1; i < 8; ++i) { float v = x[i]; if (v > bv) { bv = v; best = i; } }
  return best;
}

// --------------------------- fused prep kernel ------------------------------
// blocks [0, 4096)   : x fp32 -> bf16 (8 elems/thread)
// blocks [4096, 8192): 4 transpose+cvt jobs of 1024 blocks each
__global__ __launch_bounds__(256) void prep_kernel(
    const float* __restrict__ x, const float* __restrict__ W1,
    const float* __restrict__ W2,
    unsigned short* __restrict__ xb, unsigned short* __restrict__ w1t,
    unsigned short* __restrict__ w2t) {
  __shared__ float tile[64][65];
  const int bid = blockIdx.x;
  const int t = threadIdx.x;
  if (bid < 4096) {
    const int i = bid * 256 + t;
    const float4* xv = (const float4*)x;
    float4 v0 = xv[i * 2], v1 = xv[i * 2 + 1];
    ushort4 o0, o1;
    o0.x = f2bf(v0.x); o0.y = f2bf(v0.y); o0.z = f2bf(v0.z); o0.w = f2bf(v0.w);
    o1.x = f2bf(v1.x); o1.y = f2bf(v1.y); o1.z = f2bf(v1.z); o1.w = f2bf(v1.w);
    ((ushort4*)xb)[i * 2] = o0; ((ushort4*)xb)[i * 2 + 1] = o1;
    return;
  }
  const int op = compute_op(x);
  const int j = bid - 4096;
  const int job = j >> 10, w = j & 1023;
  const int e = job & 1;
  const bool isW1 = (job < 2);
  const int R = isW1 ? 1024 : 4096;
  const int C = isW1 ? 4096 : 1024;
  const float* W = (isW1 ? W1 : W2) + ((size_t)op * 2 + (size_t)e) * (size_t)R * C;
  unsigned short* dst0 = (isW1 ? w1t : w2t) + (size_t)e * 4096 * 1024;
  const int tc = w % (C >> 6), tr = w / (C >> 6);
  {
    const int r  = t >> 2;
    const int c0 = (t & 3) * 16;
    const float* src = W + (size_t)(tr * 64 + r) * C + tc * 64 + c0;
#pragma unroll
    for (int jj = 0; jj < 16; jj += 4) {
      float4 v = *(const float4*)(src + jj);
      tile[r][c0 + jj]     = v.x;
      tile[r][c0 + jj + 1] = v.y;
      tile[r][c0 + jj + 2] = v.z;
      tile[r][c0 + jj + 3] = v.w;
    }
  }
  __syncthreads();
  {
    const int c  = t >> 2;
    const int r0 = (t & 3) * 16;
    unsigned short* dp = dst0 + (size_t)(tc * 64 + c) * R + tr * 64 + r0;
#pragma unroll
    for (int jj = 0; jj < 16; jj += 4) {
      ushort4 o;
      o.x = f2bf(tile[r0 + jj][c]);
      o.y = f2bf(tile[r0 + jj + 1][c]);
      o.z = f2bf(tile[r0 + jj + 2][c]);
      o.w = f2bf(tile[r0 + jj + 3][c]);
      *(ushort4*)(dp + jj) = o;
    }
  }
}

// --------------------------- pipelined GEMM ---------------------------------
// C = A @ Bt^T + bias [,gelu].  A: [M][K] bf16, Bt: [N][K] bf16.
// 8 waves fixed 2M x 4N; per-wave (BM/2) x 64.
// LDS per buffer: A [BM][64] + B [BN][64] bf16; 16B chunk c of row r stored
// at c ^ (r&7) (both-sides swizzle with pre-swizzled staging source).

template<int BM, int BN>
__device__ __forceinline__ void stage_tile_all(
    const unsigned short* __restrict__ Ab,
    const unsigned short* __restrict__ Bb,
    int K, int kb, short* __restrict__ dst, int tid) {
  constexpr int SA = BM / 64, SB = BN / 64, ABK = BM * 64;
#pragma unroll
  for (int j = 0; j < SA; ++j) {
    const int ci = j * 512 + tid;
    const int row = ci >> 3;
    const int gc = (ci & 7) ^ (row & 7);
    gload_lds16(Ab + (size_t)row * K + kb + gc * 8, dst + ci * 8);
  }
#pragma unroll
  for (int j = 0; j < SB; ++j) {
    const int cj = j * 512 + tid;
    const int row = cj >> 3;
    const int gc = (cj & 7) ^ (row & 7);
    gload_lds16(Bb + (size_t)row * K + kb + gc * 8, dst + ABK + cj * 8);
  }
}

template<int BM, int BN, bool SLOW_BM, bool GELU, typename OUT_T>
__global__ __launch_bounds__(512, 2) void gemm16(
    const unsigned short* __restrict__ A,
    const unsigned short* __restrict__ Bt,
    const float* __restrict__ x_op,          // for inline op computation
    const float* __restrict__ bias_base,     // [8][2][N]
    int expert, OUT_T* __restrict__ Cout, int M, int N, int K)
{
  constexpr int BK = 64;
  constexpr int MR = BM / 32;             // 16-row frags per wave (8 or 4)
  constexpr int NR = 4;                   // 16-col frags per wave
  constexpr int S  = BM / 64 + BN / 64;   // stage instrs per K-tile (8 or 6)
  constexpr int BUF = (BM + BN) * BK;     // shorts per double-buffer half
  static_assert(BN == 256, "wave grid 2Mx4N assumes BN=256");
  __shared__ short smem[2 * BUF];

  const int tid  = threadIdx.x;
  const int wid  = tid >> 6, lane = tid & 63;
  const int wm   = wid >> 2, wn = wid & 3;
  const int lq   = lane >> 4, lr = lane & 15;

  // XCD-aware bijective swizzle (nwg % 8 == 0); slow index keeps the small
  // reused panel resident in the XCD's L2.
  const int nwg = gridDim.x;
  const int id  = blockIdx.x;
  const int s   = (id & 7) * (nwg >> 3) + (id >> 3);
  int bm, bn;
  if constexpr (SLOW_BM) { const int nbn = N / BN; bm = s / nbn; bn = s % nbn; }
  else                   { const int nbm = M / BM; bn = s / nbm; bm = s % nbm; }

  const unsigned short* Ab = A  + (size_t)bm * BM * K;
  const unsigned short* Bb = Bt + (size_t)bn * BN * K;

  f32x4 acc[MR][NR] = {};

  // prologue: stage all of K-tile 0 into buffer 0
  stage_tile_all<BM, BN>(Ab, Bb, K, 0, smem, tid);

  const int nkt = K / BK;
  for (int t = 0; t < nkt; ++t) {
    const char* cA = (const char*)(smem + (t & 1) * BUF);
    const char* cB = cA + BM * BK * 2;
    short* nxt = smem + ((t + 1) & 1) * BUF;

    // tile top: issue ALL of t+1's stages, counted wait for t's only (T4).
    if (t + 1 < nkt) { stage_tile_all<BM, BN>(Ab, Bb, K, (t + 1) * BK, nxt, tid); wait_vm<S>(); }
    else             { wait_vm<0>(); }
    SBAR;   // all waves' t-loads landed -> cur readable

    // ---- tile body: NO intra-tile sync; compiler schedules reads vs MFMAs
    //      with fine-grained lgkmcnt (m97-style).
#pragma unroll
    for (int ks = 0; ks < 2; ++ks) {
      short8 bf[NR];
#pragma unroll
      for (int n = 0; n < NR; ++n) {
        const int rb = wn * 64 + n * 16 + lr;
        const int ch = ((ks << 2) | lq) ^ (rb & 7);
        bf[n] = *(const short8*)(cB + rb * 128 + ch * 16);
      }
#pragma unroll
      for (int mh = 0; mh < 2; ++mh) {
        short8 af[MR / 2];
#pragma unroll
        for (int mm = 0; mm < MR / 2; ++mm) {
          const int ra = wm * (BM / 2) + (mh * (MR / 2) + mm) * 16 + lr;
          const int ch = ((ks << 2) | lq) ^ (ra & 7);
          af[mm] = *(const short8*)(cA + ra * 128 + ch * 16);
        }
#pragma unroll
        for (int mm = 0; mm < MR / 2; ++mm)
#pragma unroll
          for (int n = 0; n < NR; ++n)
            acc[mh * (MR / 2) + mm][n] = __builtin_amdgcn_mfma_f32_16x16x32_bf16(
                af[mm], bf[n], acc[mh * (MR / 2) + mm][n], 0, 0, 0);
      }
    }

    // tile end: drain my ds_reads, then barrier -> next iter may overwrite cur
    LGKM0;
    SBAR;
  }

  // Epilogue: C/D layout col=lane&15, row=(lane>>4)*4+reg [m89-verified]
  const int op = compute_op(x_op);
  const float* bias = bias_base + ((size_t)op * 2 + (size_t)expert) * (size_t)N;
#pragma unroll
  for (int f = 0; f < MR; ++f) {
    const int grow0 = bm * BM + wm * (BM / 2) + f * 16 + lq * 4;
#pragma unroll
    for (int n = 0; n < NR; ++n) {
      const int gcol = bn * BN + wn * 64 + n * 16 + lr;
      const float bv = bias[gcol];
#pragma unroll
      for (int r = 0; r < 4; ++r) {
        float v = acc[f][n][r] + bv;
        if constexpr (GELU) v = gelu_tanh(v);
        const size_t off = (size_t)(grow0 + r) * N + gcol;
        if constexpr (std::is_same<OUT_T, float>::value) Cout[off] = v;
        else Cout[off] = f2bf(v);
      }
    }
  }
}

// --------------------------- launcher ---------------------------------------
extern "C" void kernel_launch(void* const* d_in, const int* in_sizes, int n_in,
                              void* d_out, int out_size, void* d_ws, size_t ws_size,
                              hipStream_t stream) {
  const float* x  = (const float*)d_in[0];
  const float* W1 = (const float*)d_in[1];   // [8][2][1024][4096]
  const float* b1 = (const float*)d_in[2];   // [8][2][4096]
  const float* W2 = (const float*)d_in[3];   // [8][2][4096][1024]
  const float* b2 = (const float*)d_in[4];   // [8][2][1024]
  float* out = (float*)d_out;

  const int D = 1024, F = 4096, M = 8192;    // M = B*S = 4*2048

  // ws layout: [xb 16.8MB][w1t 16.8MB][w2t 16.8MB][h 67.1MB]
  char* ws = (char*)d_ws;
  unsigned short* xb  = (unsigned short*)ws;
  unsigned short* w1t = (unsigned short*)(ws + (size_t)M * D * 2);
  unsigned short* w2t = (unsigned short*)(ws + (size_t)M * D * 2 + (size_t)2 * D * F * 2);
  unsigned short* h   = (unsigned short*)(ws + (size_t)M * D * 2 + (size_t)4 * D * F * 2);
  unsigned short* x1b = (unsigned short*)d_out;  // stage-0 output parked in d_out

  // one fused prep dispatch: cvt(x) + 4 transpose/cvt jobs
  prep_kernel<<<4096 + 4 * 1024, 256, 0, stream>>>(x, W1, W2, xb, w1t, w2t);

  // GEMM1: M=8192,N=4096,K=1024  BM=256,BN=256, grid 512, bm-slow chunks
  // GEMM2: M=8192,N=1024,K=4096  BM=128,BN=256, grid 256, bn-slow chunks
  // expert 0
  gemm16<256, 256, true,  true,  unsigned short><<<(M/256)*(F/256), 512, 0, stream>>>(xb,  w1t,                 x, b1, 0, h,   M, F, D);
  gemm16<128, 256, false, false, unsigned short><<<(M/128)*(D/256), 512, 0, stream>>>(h,   w2t,                 x, b2, 0, x1b, M, D, F);
  // expert 1
  gemm16<256, 256, true,  true,  unsigned short><<<(M/256)*(F/256), 512, 0, stream>>>(x1b, w1t + (size_t)F * D, x, b1, 1, h,   M, F, D);
  gemm16<128, 256, false, false, float         ><<<(M/128)*(D/256), 512, 0, stream>>>(h,   w2t + (size_t)D * F, x, b2, 1, out, M, D, F);
}